// Round 4
// baseline (96.533 us; speedup 1.0000x reference)
//
#include <hip/hip_runtime.h>

typedef __bf16 bf16x8 __attribute__((ext_vector_type(8)));
typedef float f32x4 __attribute__((ext_vector_type(4)));

__device__ __forceinline__ unsigned short f2bf(float f) {
  union { float f; unsigned u; } x; x.f = f;
  unsigned r = x.u + 0x7fffu + ((x.u >> 16) & 1u);
  return (unsigned short)(r >> 16);
}

__device__ __forceinline__ void gl_lds16(const void* g, void* l) {
  __builtin_amdgcn_global_load_lds(
      (const __attribute__((address_space(1))) void*)g,
      (__attribute__((address_space(3))) void*)l, 16, 0, 0);
}

// convert 16 consecutive floats at p into two bf16x8 halves
__device__ __forceinline__ void cvt16(const float* p, bf16x8& h0, bf16x8& h1) {
  float4 a0 = *(const float4*)(p);
  float4 a1 = *(const float4*)(p + 4);
  float4 a2 = *(const float4*)(p + 8);
  float4 a3 = *(const float4*)(p + 12);
  h0[0] = (__bf16)a0.x; h0[1] = (__bf16)a0.y; h0[2] = (__bf16)a0.z; h0[3] = (__bf16)a0.w;
  h0[4] = (__bf16)a1.x; h0[5] = (__bf16)a1.y; h0[6] = (__bf16)a1.z; h0[7] = (__bf16)a1.w;
  h1[0] = (__bf16)a2.x; h1[1] = (__bf16)a2.y; h1[2] = (__bf16)a2.z; h1[3] = (__bf16)a2.w;
  h1[4] = (__bf16)a3.x; h1[5] = (__bf16)a3.y; h1[6] = (__bf16)a3.z; h1[7] = (__bf16)a3.w;
}

// ---------------- fp32 -> bf16 convert (w_conv only) ----------------
__global__ __launch_bounds__(256) void convert_bf16(const float* __restrict__ in,
                                                    unsigned short* __restrict__ out,
                                                    long n) {
  long i = ((long)blockIdx.x * 256 + threadIdx.x) * 8;
  if (i >= n) return;
  bf16x8 h0, h1;
  cvt16(&in[i & ~15L], h0, h1);
  bf16x8 h = (i & 8) ? h1 : h0;
  *(bf16x8*)&out[i] = h;
}

// ---------------- x_middle [b][c][n] fp32 -> vt [b][n][c] bf16 ----------------
__global__ __launch_bounds__(256) void transpose_v(const float* __restrict__ xm,
                                                   unsigned short* __restrict__ vt) {
  __shared__ float t[32][33];
  const int b = blockIdx.z;
  const int n0 = blockIdx.x * 32;
  const int c0 = blockIdx.y * 32;
  const int tid = threadIdx.x;
  const int r = tid >> 3;          // 0..31
  const int q4 = (tid & 7) * 4;    // 0,4,...,28

  float4 v = *(const float4*)&xm[((long)b * 256 + c0 + r) * 4096 + n0 + q4];
  t[r][q4 + 0] = v.x; t[r][q4 + 1] = v.y; t[r][q4 + 2] = v.z; t[r][q4 + 3] = v.w;
  __syncthreads();
  ushort4 o;
  o.x = f2bf(t[q4 + 0][r]);
  o.y = f2bf(t[q4 + 1][r]);
  o.z = f2bf(t[q4 + 2][r]);
  o.w = f2bf(t[q4 + 3][r]);
  *(ushort4*)&vt[((long)b * 4096 + n0 + r) * 256 + c0 + q4] = o;
}

// ---- sim split-K GEMM with fused fp32->bf16 convert ----
// simP[q][b][256][256] = 0.0625 * (x_panel x_panel^T), K-chunk q of 4 (K=1024 each)
__global__ __launch_bounds__(256) void sim_split(const float* __restrict__ x,
                                                 float* __restrict__ simP) {
  __shared__ __align__(16) unsigned short As[4096];
  __shared__ __align__(16) unsigned short Bs[4096];

  const int j = blockIdx.x;            // 0..1023
  const int xcd = j & 7, s = j >> 3;   // s 0..127
  const int p = xcd * 8 + (s >> 4);    // panel 0..63
  const int t = s & 15;                // tile in panel
  const int b = p >> 2, q = p & 3;
  const int tm = t >> 2, tn = t & 3;

  const int tid = threadIdx.x;
  const int wave = tid >> 6, lane = tid & 63;
  const float* xA = x + (long)b * 1048576 + (long)(tm * 64) * 4096;
  const float* xB = x + (long)b * 1048576 + (long)(tn * 64) * 4096;
  const bool diag = (tm == tn);

  const int r = tid >> 2, kq = tid & 3;  // staging: row 0..63, k-quarter
  const int wr = (wave >> 1) * 32, wc = (wave & 1) * 32;
  const int fr = lane & 15, fq = lane >> 4;

  f32x4 acc[2][2];
#pragma unroll
  for (int i = 0; i < 2; ++i)
#pragma unroll
    for (int jj = 0; jj < 2; ++jj) acc[i][jj] = (f32x4)0.f;

  const int c0 = ((kq * 2) ^ (r & 7)) * 8;
  const int c1 = ((kq * 2 + 1) ^ (r & 7)) * 8;

  for (int k0 = q * 1024; k0 < q * 1024 + 1024; k0 += 64) {
    {
      bf16x8 h0, h1;
      cvt16(xA + (long)r * 4096 + k0 + kq * 16, h0, h1);
      *(bf16x8*)&As[r * 64 + c0] = h0;
      *(bf16x8*)&As[r * 64 + c1] = h1;
      if (!diag) {
        cvt16(xB + (long)r * 4096 + k0 + kq * 16, h0, h1);
        *(bf16x8*)&Bs[r * 64 + c0] = h0;
        *(bf16x8*)&Bs[r * 64 + c1] = h1;
      }
    }
    __syncthreads();
    const unsigned short* Bp = diag ? As : Bs;
#pragma unroll
    for (int kk = 0; kk < 2; ++kk) {
      bf16x8 af[2], bfr[2];
#pragma unroll
      for (int mi = 0; mi < 2; ++mi) {
        int row = wr + mi * 16 + fr;
        int chunk = (kk * 4 + fq) ^ (row & 7);
        af[mi] = *(const bf16x8*)&As[row * 64 + chunk * 8];
      }
#pragma unroll
      for (int ni = 0; ni < 2; ++ni) {
        int row = wc + ni * 16 + fr;
        int chunk = (kk * 4 + fq) ^ (row & 7);
        bfr[ni] = *(const bf16x8*)&Bp[row * 64 + chunk * 8];
      }
#pragma unroll
      for (int mi = 0; mi < 2; ++mi)
#pragma unroll
        for (int ni = 0; ni < 2; ++ni)
          acc[mi][ni] =
              __builtin_amdgcn_mfma_f32_16x16x32_bf16(af[mi], bfr[ni], acc[mi][ni], 0, 0, 0);
    }
    __syncthreads();
  }

  float* O = simP + (long)(q * 16 + b) * 65536;
#pragma unroll
  for (int mi = 0; mi < 2; ++mi)
#pragma unroll
    for (int ni = 0; ni < 2; ++ni)
#pragma unroll
      for (int jj = 0; jj < 4; ++jj) {
        const int rr = tm * 64 + wr + mi * 16 + fq * 4 + jj;
        const int cc = tn * 64 + wc + ni * 16 + fr;
        O[(long)rr * 256 + cc] = 0.0625f * acc[mi][ni][jj];
      }
}

// -------- softmax over d, 4-way split-K reduce; output transposed Ps[b][d][c] bf16 ----
__global__ __launch_bounds__(256) void softmax4(const float* __restrict__ simP,
                                                unsigned short* __restrict__ Ps) {
  const int wave = threadIdx.x >> 6;
  const int lane = threadIdx.x & 63;
  const int gid = blockIdx.x * 4 + wave;  // row index b*256+c
  const int b = gid >> 8;
  const int c = gid & 255;

  float4 v = make_float4(0.f, 0.f, 0.f, 0.f);
#pragma unroll
  for (int q = 0; q < 4; ++q) {
    float4 pv = *(const float4*)&simP[(long)(q * 16 + b) * 65536 + (long)c * 256 + lane * 4];
    v.x += pv.x; v.y += pv.y; v.z += pv.z; v.w += pv.w;
  }
  float m = fmaxf(fmaxf(v.x, v.y), fmaxf(v.z, v.w));
#pragma unroll
  for (int off = 32; off; off >>= 1) m = fmaxf(m, __shfl_xor(m, off));
  float e0 = expf(v.x - m), e1 = expf(v.y - m), e2 = expf(v.z - m), e3 = expf(v.w - m);
  float s = e0 + e1 + e2 + e3;
#pragma unroll
  for (int off = 32; off; off >>= 1) s += __shfl_xor(s, off);
  const float inv = 1.0f / s;
  unsigned short* colp = Ps + (long)b * 65536 + c;
  colp[(lane * 4 + 0) * 256] = f2bf(e0 * inv);
  colp[(lane * 4 + 1) * 256] = f2bf(e1 * inv);
  colp[(lane * 4 + 2) * 256] = f2bf(e2 * inv);
  colp[(lane * 4 + 3) * 256] = f2bf(e3 * inv);
}

// -------- Ab = W * P + I  (NT, M=N=K=256, bf16 out; residual folded as +I) --------
__global__ __launch_bounds__(256) void gemm_wp(const unsigned short* __restrict__ wb,
                                               const unsigned short* __restrict__ Ps,
                                               unsigned short* __restrict__ Ab) {
  __shared__ __align__(16) unsigned short As[4096];
  __shared__ __align__(16) unsigned short Bs[4096];
  const int b = blockIdx.y;
  const int tm = blockIdx.x >> 2, tn = blockIdx.x & 3;
  const int tid = threadIdx.x;
  const int wave = tid >> 6, lane = tid & 63;

  const unsigned short* A = wb + (long)(tm * 64) * 256;
  const unsigned short* B = Ps + (long)b * 65536 + (long)(tn * 64) * 256;

  const int srow = wave * 16 + (lane >> 3);
  const int schunk = (lane & 7) ^ (lane >> 3);
  const int wr = (wave >> 1) * 32, wc = (wave & 1) * 32;
  const int fr = lane & 15, fq = lane >> 4;

  f32x4 acc[2][2];
#pragma unroll
  for (int i = 0; i < 2; ++i)
#pragma unroll
    for (int jj = 0; jj < 2; ++jj) acc[i][jj] = (f32x4)0.f;

  for (int k0 = 0; k0 < 256; k0 += 64) {
    gl_lds16(A + (long)srow * 256 + k0 + schunk * 8, &As[(wave * 2 + 0) * 512]);
    gl_lds16(A + (long)(srow + 8) * 256 + k0 + schunk * 8, &As[(wave * 2 + 1) * 512]);
    gl_lds16(B + (long)srow * 256 + k0 + schunk * 8, &Bs[(wave * 2 + 0) * 512]);
    gl_lds16(B + (long)(srow + 8) * 256 + k0 + schunk * 8, &Bs[(wave * 2 + 1) * 512]);
    __syncthreads();
#pragma unroll
    for (int kk = 0; kk < 2; ++kk) {
      bf16x8 af[2], bfr[2];
#pragma unroll
      for (int mi = 0; mi < 2; ++mi) {
        int row = wr + mi * 16 + fr;
        int chunk = (kk * 4 + fq) ^ (row & 7);
        af[mi] = *(const bf16x8*)&As[row * 64 + chunk * 8];
      }
#pragma unroll
      for (int ni = 0; ni < 2; ++ni) {
        int row = wc + ni * 16 + fr;
        int chunk = (kk * 4 + fq) ^ (row & 7);
        bfr[ni] = *(const bf16x8*)&Bs[row * 64 + chunk * 8];
      }
#pragma unroll
      for (int mi = 0; mi < 2; ++mi)
#pragma unroll
        for (int ni = 0; ni < 2; ++ni)
          acc[mi][ni] =
              __builtin_amdgcn_mfma_f32_16x16x32_bf16(af[mi], bfr[ni], acc[mi][ni], 0, 0, 0);
    }
    __syncthreads();
  }

  unsigned short* O = Ab + (long)b * 65536;
#pragma unroll
  for (int mi = 0; mi < 2; ++mi)
#pragma unroll
    for (int ni = 0; ni < 2; ++ni)
#pragma unroll
      for (int jj = 0; jj < 4; ++jj) {
        const int rr = tm * 64 + wr + mi * 16 + fq * 4 + jj;
        const int cc = tn * 64 + wc + ni * 16 + fr;
        float val = acc[mi][ni][jj] + (rr == cc ? 1.0f : 0.0f);  // residual: +I
        O[(long)rr * 256 + cc] = f2bf(val);
      }
}

// -------- out = (W*P + I) * v  (NT bf16; A staged once, B 2-phase pipelined) ----
// tile 64o x 64n, K=256. grid 4096 flat, XCD-clustered (tm-quads of same (b,tn)
// adjacent on one XCD so the vt panel is an L2 hit).
__global__ __launch_bounds__(256) void gemm_out(const unsigned short* __restrict__ Ab,
                                                const unsigned short* __restrict__ vt,
                                                float* __restrict__ out) {
  __shared__ __align__(16) unsigned short As[64 * 256];    // whole A tile [o][d], swizzled
  __shared__ __align__(16) unsigned short Bs[2][64 * 64];  // [n][d] slab, dbuf, swizzled

  const int j = blockIdx.x;            // 0..4095
  const int xcd = j & 7, s = j >> 3;   // s 0..511
  const int tm = s & 3;
  const int g = xcd * 128 + (s >> 2);  // 0..1023
  const int b = g >> 6, tn = g & 63;

  const int tid = threadIdx.x;
  const int wave = tid >> 6, lane = tid & 63;

  const unsigned short* A = Ab + (long)b * 65536 + (long)(tm * 64) * 256;
  const unsigned short* Bbase = vt + (long)b * 4096 * 256 + (long)(tn * 64) * 256;
  float* Ob = out + (long)b * 1048576;

  const int srow = wave * 16 + (lane >> 3);
  const int schunk = (lane & 7) ^ (lane >> 3);
  const int wr = (wave >> 1) * 32, wc = (wave & 1) * 32;
  const int fr = lane & 15, fq = lane >> 4;

  // ---- stage whole A tile (64 rows x 256 d, 32 KB) once; pre-swizzled source ----
  {
    const int c_dst = lane & 31;
#pragma unroll
    for (int i = 0; i < 8; ++i) {
      const int g8 = i * 4 + wave;          // 1KB group 0..31
      const int r = g8 * 2 + (lane >> 5);   // dest row 0..63
      const int c_log = c_dst ^ (r & 7);    // logical 16B chunk 0..31
      gl_lds16(A + (long)r * 256 + c_log * 8, &As[g8 * 512]);
    }
  }
  // ---- stage B slab 0 ----
  gl_lds16(Bbase + (long)srow * 256 + 0 * 64 + schunk * 8, &Bs[0][(wave * 2 + 0) * 512]);
  gl_lds16(Bbase + (long)(srow + 8) * 256 + 0 * 64 + schunk * 8, &Bs[0][(wave * 2 + 1) * 512]);
  __syncthreads();

  f32x4 acc[2][2];
#pragma unroll
  for (int i = 0; i < 2; ++i)
#pragma unroll
    for (int jj = 0; jj < 2; ++jj) acc[i][jj] = (f32x4)0.f;

#pragma unroll
  for (int t = 0; t < 4; ++t) {
    if (t < 3) {  // prefetch next B slab into the other buffer
      const int d1 = (t + 1) * 64;
      gl_lds16(Bbase + (long)srow * 256 + d1 + schunk * 8,
               &Bs[(t + 1) & 1][(wave * 2 + 0) * 512]);
      gl_lds16(Bbase + (long)(srow + 8) * 256 + d1 + schunk * 8,
               &Bs[(t + 1) & 1][(wave * 2 + 1) * 512]);
    }
    const unsigned short* Bcur = Bs[t & 1];
#pragma unroll
    for (int kk = 0; kk < 2; ++kk) {
      bf16x8 af[2], bfr[2];
#pragma unroll
      for (int mi = 0; mi < 2; ++mi) {
        int row = wr + mi * 16 + fr;
        int chunk = (t * 8 + kk * 4 + fq) ^ (row & 7);
        af[mi] = *(const bf16x8*)&As[row * 256 + chunk * 8];
      }
#pragma unroll
      for (int ni = 0; ni < 2; ++ni) {
        int row = wc + ni * 16 + fr;
        int chunk = (kk * 4 + fq) ^ (row & 7);
        bfr[ni] = *(const bf16x8*)&Bcur[row * 64 + chunk * 8];
      }
#pragma unroll
      for (int mi = 0; mi < 2; ++mi)
#pragma unroll
        for (int ni = 0; ni < 2; ++ni)
          acc[mi][ni] =
              __builtin_amdgcn_mfma_f32_16x16x32_bf16(af[mi], bfr[ni], acc[mi][ni], 0, 0, 0);
    }
    __syncthreads();  // drains this iter's prefetch; guards dbuf reuse
  }

#pragma unroll
  for (int mi = 0; mi < 2; ++mi)
#pragma unroll
    for (int ni = 0; ni < 2; ++ni)
#pragma unroll
      for (int jj = 0; jj < 4; ++jj) {
        const int rr = tm * 64 + wr + mi * 16 + fq * 4 + jj;
        const int cc = tn * 64 + wc + ni * 16 + fr;
        Ob[(long)rr * 4096 + cc] = acc[mi][ni][jj];
      }
}

extern "C" void kernel_launch(void* const* d_in, const int* in_sizes, int n_in,
                              void* d_out, int out_size, void* d_ws, size_t ws_size,
                              hipStream_t stream) {
  const float* x = (const float*)d_in[0];
  const float* xm = (const float*)d_in[1];
  const float* w = (const float*)d_in[2];
  float* out = (float*)d_out;

  const long B = 16, C = 256, N = 4096;

  float* simP = (float*)d_ws;                                    // [4][B][C][C] fp32 (16.8 MB)
  unsigned short* Ps = (unsigned short*)(simP + 4 * B * C * C);  // [B][d][c] bf16 (2 MB)
  unsigned short* Ab = Ps + B * C * C;                           // [B][o][d] bf16 (2 MB)
  unsigned short* wb = Ab + B * C * C;                           // [o][c] bf16 (128 KB)
  unsigned short* vt = wb + C * C;                               // [B][n][c] bf16 (33.6 MB)

  // 1) w_conv -> bf16
  convert_bf16<<<dim3(32), dim3(256), 0, stream>>>(w, wb, C * C);
  // 2) x_middle -> vt (transposed bf16)
  transpose_v<<<dim3(128, 8, 16), dim3(256), 0, stream>>>(xm, vt);
  // 3) simP = split-K(4) partials of scale * q q^T (x converted in-kernel)
  sim_split<<<dim3(1024), dim3(256), 0, stream>>>(x, simP);
  // 4) P = softmax(sum_q simP), stored transposed
  softmax4<<<dim3(1024), dim3(256), 0, stream>>>(simP, Ps);
  // 5) Ab = W * P + I   (residual folded into Ab)
  gemm_wp<<<dim3(16, 16), dim3(256), 0, stream>>>(wb, Ps, Ab);
  // 6) out = Ab * v
  gemm_out<<<dim3(4096), dim3(256), 0, stream>>>(Ab, vt, out);
}